// Round 1
// baseline (1216.699 us; speedup 1.0000x reference)
//
#include <hip/hip_runtime.h>
#include <hip/hip_bf16.h>
#include <stdint.h>

// LSTM cell fused kernel for MI355X (gfx950).
// gates = x*Wx^T + h*Wh^T + bx + bh ; i,f,o=sigmoid, g=tanh
// c_new = f*c + i*g ; h_new = o*tanh(c_new)
// Strategy: split-bf16 (hi/lo) MFMA GEMM, 3 terms (hh, hl, lh), err ~2^-16.
// Block = 256 thr = 4 waves; wave w computes gate w's 64x64 tile.
// A (x/h rows) staged hi/lo in LDS [64][40] ushort (padded -> 2-way free).
// W fragments loaded global->reg directly (L2-resident via XCD swizzle).

typedef float        f32x4 __attribute__((ext_vector_type(4)));
typedef short        s16x8 __attribute__((ext_vector_type(8)));
typedef unsigned int u32x4 __attribute__((ext_vector_type(4)));
typedef unsigned int u32x2 __attribute__((ext_vector_type(2)));

#define BH_TOT 8388608  // B*H = 4096*2048

__device__ __forceinline__ void splitf4(f32x4 v, u32x2& hp, u32x2& lp) {
  unsigned int u0 = __float_as_uint(v[0]), u1 = __float_as_uint(v[1]);
  unsigned int u2 = __float_as_uint(v[2]), u3 = __float_as_uint(v[3]);
  float d0 = v[0] - __uint_as_float(u0 & 0xFFFF0000u);
  float d1 = v[1] - __uint_as_float(u1 & 0xFFFF0000u);
  float d2 = v[2] - __uint_as_float(u2 & 0xFFFF0000u);
  float d3 = v[3] - __uint_as_float(u3 & 0xFFFF0000u);
  hp[0] = (u0 >> 16) | (u1 & 0xFFFF0000u);
  hp[1] = (u2 >> 16) | (u3 & 0xFFFF0000u);
  unsigned int l0 = __float_as_uint(d0), l1 = __float_as_uint(d1);
  unsigned int l2 = __float_as_uint(d2), l3 = __float_as_uint(d3);
  lp[0] = (l0 >> 16) | (l1 & 0xFFFF0000u);
  lp[1] = (l2 >> 16) | (l3 & 0xFFFF0000u);
}

__device__ __forceinline__ void splitw(f32x4 w0, f32x4 w1, s16x8& hi, s16x8& lo) {
  u32x2 h0, l0, h1, l1;
  splitf4(w0, h0, l0);
  splitf4(w1, h1, l1);
  u32x4 hu = {h0[0], h0[1], h1[0], h1[1]};
  u32x4 lu = {l0[0], l0[1], l1[0], l1[1]};
  hi = __builtin_bit_cast(s16x8, hu);
  lo = __builtin_bit_cast(s16x8, lu);
}

__device__ __forceinline__ float sigmoidf_(float x) {
  return 1.0f / (1.0f + __expf(-x));
}

__global__ __launch_bounds__(256, 2) void lstm_fused(
    const float* __restrict__ x, const float* __restrict__ h,
    const float* __restrict__ cold, const float* __restrict__ Wx,
    const float* __restrict__ bx, const float* __restrict__ Wh,
    const float* __restrict__ bh, float* __restrict__ out) {
  // smem: staging Ah[64*40] us (5120B) + Al (5120B); epilogue 4*64*68 f32 = 69632B
  __shared__ unsigned char smem[69632];
  unsigned short* Ah = (unsigned short*)smem;
  unsigned short* Al = (unsigned short*)(smem + 5120);
  float* gl = (float*)smem;

  const int tid = threadIdx.x;
  const int lane = tid & 63;
  const int wid = tid >> 6;  // gate id 0..3 (i,f,g,o)

  // XCD-bijective swizzle: 2048 wgs = 8 XCDs x 256; m-major within an XCD
  const int swz = (blockIdx.x & 7) * 256 + (blockIdx.x >> 3);
  const int bn = swz >> 6;   // 0..31  (col tile within H)
  const int bm = swz & 63;   // 0..63  (batch tile)
  const int row0 = bm * 64;
  const int col0 = bn * 64;

  // A staging mapping: f4 idx {tid, tid+256}: row = idx>>3, kc = (idx&7)*4
  const int ar0 = tid >> 3;         // 0..31
  const int akc = (tid & 7) << 2;   // 0,4,..,28
  const int wcol = lane & 15;
  const int kch = (lane >> 4) << 3; // 0,8,16,24

  f32x4 acc[4][4];
#pragma unroll
  for (int i = 0; i < 4; ++i)
#pragma unroll
    for (int j = 0; j < 4; ++j) acc[i][j] = (f32x4)0.0f;

#pragma unroll
  for (int ph = 0; ph < 2; ++ph) {
    const float* Ap = ph ? h : x;
    const float* Wp = ph ? Wh : Wx;
    const float* arow0 = Ap + (size_t)(row0 + ar0) * 2048 + akc;
    const float* arow1 = arow0 + 32 * 2048;
    const float* wb[4];
#pragma unroll
    for (int tn = 0; tn < 4; ++tn)
      wb[tn] = Wp + (size_t)(wid * 2048 + col0 + tn * 16 + wcol) * 2048 + kch;

    f32x4 a0 = *(const f32x4*)(arow0);
    f32x4 a1 = *(const f32x4*)(arow1);

    for (int kt = 0; kt < 64; ++kt) {
      const int k0 = kt << 5;
      // issue W fragment loads early (latency hidden under staging+ds_reads)
      f32x4 wr[4][2];
#pragma unroll
      for (int tn = 0; tn < 4; ++tn) {
        wr[tn][0] = *(const f32x4*)(wb[tn] + k0);
        wr[tn][1] = *(const f32x4*)(wb[tn] + k0 + 4);
      }
      // stage A tile (convert f32 -> bf16 hi/lo) into LDS
      {
        u32x2 hp, lp;
        splitf4(a0, hp, lp);
        *(u32x2*)(Ah + ar0 * 40 + akc) = hp;
        *(u32x2*)(Al + ar0 * 40 + akc) = lp;
        splitf4(a1, hp, lp);
        *(u32x2*)(Ah + (ar0 + 32) * 40 + akc) = hp;
        *(u32x2*)(Al + (ar0 + 32) * 40 + akc) = lp;
      }
      __syncthreads();
      // prefetch next A tile
      if (kt != 63) {
        a0 = *(const f32x4*)(arow0 + k0 + 32);
        a1 = *(const f32x4*)(arow1 + k0 + 32);
      }
      // A fragments from LDS (16B aligned, 2-way-free bank pattern)
      s16x8 ah[4], al[4];
#pragma unroll
      for (int tm = 0; tm < 4; ++tm) {
        const int off = (tm * 16 + wcol) * 40 + kch;
        ah[tm] = *(const s16x8*)(Ah + off);
        al[tm] = *(const s16x8*)(Al + off);
      }
      // convert W registers -> bf16 hi/lo fragments
      s16x8 wh[4], wl[4];
#pragma unroll
      for (int tn = 0; tn < 4; ++tn) splitw(wr[tn][0], wr[tn][1], wh[tn], wl[tn]);
      // 3-term split MFMA, term-major (16 independent acc tiles per term)
#pragma unroll
      for (int tm = 0; tm < 4; ++tm)
#pragma unroll
        for (int tn = 0; tn < 4; ++tn)
          acc[tm][tn] = __builtin_amdgcn_mfma_f32_16x16x32_bf16(
              ah[tm], wh[tn], acc[tm][tn], 0, 0, 0);
#pragma unroll
      for (int tm = 0; tm < 4; ++tm)
#pragma unroll
        for (int tn = 0; tn < 4; ++tn)
          acc[tm][tn] = __builtin_amdgcn_mfma_f32_16x16x32_bf16(
              ah[tm], wl[tn], acc[tm][tn], 0, 0, 0);
#pragma unroll
      for (int tm = 0; tm < 4; ++tm)
#pragma unroll
        for (int tn = 0; tn < 4; ++tn)
          acc[tm][tn] = __builtin_amdgcn_mfma_f32_16x16x32_bf16(
              al[tm], wh[tn], acc[tm][tn], 0, 0, 0);
      __syncthreads();
    }
  }

  // ---- epilogue: exchange gate tiles via LDS, then LSTM pointwise ----
  {
    const int rbase = (lane >> 4) << 2;
#pragma unroll
    for (int tm = 0; tm < 4; ++tm)
#pragma unroll
      for (int tn = 0; tn < 4; ++tn) {
        const int r = tm * 16 + rbase;
        const int cc = tn * 16 + wcol;
#pragma unroll
        for (int i = 0; i < 4; ++i)
          gl[wid * 4352 + (r + i) * 68 + cc] = acc[tm][tn][i];
      }
  }
  __syncthreads();

  const int ecol = (tid & 15) << 2;  // 0..60
  const int er0 = tid >> 4;          // 0..15
  const int cg = col0 + ecol;
  f32x4 bi = *(const f32x4*)(bx + cg) + *(const f32x4*)(bh + cg);
  f32x4 bf = *(const f32x4*)(bx + 2048 + cg) + *(const f32x4*)(bh + 2048 + cg);
  f32x4 bg = *(const f32x4*)(bx + 4096 + cg) + *(const f32x4*)(bh + 4096 + cg);
  f32x4 bo = *(const f32x4*)(bx + 6144 + cg) + *(const f32x4*)(bh + 6144 + cg);
#pragma unroll
  for (int j = 0; j < 4; ++j) {
    const int r = er0 + j * 16;
    const size_t gbase = (size_t)(row0 + r) * 2048 + cg;
    f32x4 gi = *(const f32x4*)&gl[0 * 4352 + r * 68 + ecol] + bi;
    f32x4 gf = *(const f32x4*)&gl[1 * 4352 + r * 68 + ecol] + bf;
    f32x4 gg = *(const f32x4*)&gl[2 * 4352 + r * 68 + ecol] + bg;
    f32x4 go = *(const f32x4*)&gl[3 * 4352 + r * 68 + ecol] + bo;
    f32x4 cv = *(const f32x4*)(cold + gbase);
    f32x4 cn, hn;
#pragma unroll
    for (int e = 0; e < 4; ++e) {
      float iv = sigmoidf_(gi[e]);
      float fv = sigmoidf_(gf[e]);
      float gv = tanhf(gg[e]);
      float ov = sigmoidf_(go[e]);
      float c2 = fv * cv[e] + iv * gv;
      cn[e] = c2;
      hn[e] = ov * tanhf(c2);
    }
    *(f32x4*)(out + gbase) = hn;
    *(f32x4*)(out + BH_TOT + gbase) = cn;
  }
}

extern "C" void kernel_launch(void* const* d_in, const int* in_sizes, int n_in,
                              void* d_out, int out_size, void* d_ws,
                              size_t ws_size, hipStream_t stream) {
  const float* x = (const float*)d_in[0];
  const float* h = (const float*)d_in[1];
  const float* c = (const float*)d_in[2];
  const float* Wx = (const float*)d_in[3];
  const float* bx = (const float*)d_in[4];
  const float* Wh = (const float*)d_in[5];
  const float* bh = (const float*)d_in[6];
  float* out = (float*)d_out;
  dim3 grid(2048), block(256);
  hipLaunchKernelGGL(lstm_fused, grid, block, 0, stream, x, h, c, Wx, bx, Wh,
                     bh, out);
}

// Round 3
// 921.781 us; speedup vs baseline: 1.3199x; 1.3199x over previous
//
#include <hip/hip_runtime.h>
#include <hip/hip_bf16.h>
#include <stdint.h>

// LSTM cell, MI355X. Two-stage plan:
//   stage 1: convert W=[Wx|Wh] and A=[x|h] to bf16 hi/lo planes in d_ws.
//   stage 2: 3-term split-bf16 MFMA GEMM (ah*wh + ah*wl + al*wh), m201-style
//            6-phase schedule with counted vmcnt + fused LSTM epilogue.
// Fallback (ws too small): round-1 kernel (known-pass, 1186us).

typedef float        f32x4 __attribute__((ext_vector_type(4)));
typedef short        s16x8 __attribute__((ext_vector_type(8)));
typedef unsigned int u32x4 __attribute__((ext_vector_type(4)));
typedef unsigned int u32x2 __attribute__((ext_vector_type(2)));
typedef unsigned short ushort_t;

#define BH_TOT 8388608   // B*H
#define NT 128           // K-tiles of 32 over K_cat=4096
#define ALO_B 33554432   // Alo - Ahi (bytes)
#define WLO_B 67108864   // Wlo - Whi (bytes)

__device__ __forceinline__ void splitf4(f32x4 v, u32x2& hp, u32x2& lp) {
  unsigned int u0 = __float_as_uint(v[0]), u1 = __float_as_uint(v[1]);
  unsigned int u2 = __float_as_uint(v[2]), u3 = __float_as_uint(v[3]);
  float d0 = v[0] - __uint_as_float(u0 & 0xFFFF0000u);
  float d1 = v[1] - __uint_as_float(u1 & 0xFFFF0000u);
  float d2 = v[2] - __uint_as_float(u2 & 0xFFFF0000u);
  float d3 = v[3] - __uint_as_float(u3 & 0xFFFF0000u);
  hp[0] = (u0 >> 16) | (u1 & 0xFFFF0000u);
  hp[1] = (u2 >> 16) | (u3 & 0xFFFF0000u);
  unsigned int l0 = __float_as_uint(d0), l1 = __float_as_uint(d1);
  unsigned int l2 = __float_as_uint(d2), l3 = __float_as_uint(d3);
  lp[0] = (l0 >> 16) | (l1 & 0xFFFF0000u);
  lp[1] = (l2 >> 16) | (l3 & 0xFFFF0000u);
}

__device__ __forceinline__ float sigmoidf_(float x) {
  return 1.0f / (1.0f + __expf(-x));
}

// ---------------- stage 1: split-conversion ----------------
// src [rows][2048] f32 -> dhi/dlo [rows][4096] bf16 at column colOff.
__global__ __launch_bounds__(256) void conv_split(
    const float* __restrict__ src, ushort_t* __restrict__ dhi,
    ushort_t* __restrict__ dlo, int n4, int colOff) {
  const int stride = gridDim.x * blockDim.x;
  for (int i = blockIdx.x * blockDim.x + threadIdx.x; i < n4; i += stride) {
    const int row = i >> 9;           // srcK/4 == 512
    const int c4 = (i & 511) << 2;
    f32x4 v = *(const f32x4*)(src + ((size_t)i << 2));
    u32x2 hp, lp;
    splitf4(v, hp, lp);
    const size_t off = (size_t)row * 4096 + colOff + c4;
    *(u32x2*)(dhi + off) = hp;
    *(u32x2*)(dlo + off) = lp;
  }
}

// ---------------- stage 2: 6-phase split GEMM ----------------
__device__ __forceinline__ void glds16(const void* g, void* l) {
  __builtin_amdgcn_global_load_lds(
      (const __attribute__((address_space(1))) unsigned int*)g,
      (__attribute__((address_space(3))) unsigned int*)l, 16, 0, 0);
}

// plane [256][32] bf16, 16B slots XOR-swizzled by (row&3)
__device__ __forceinline__ s16x8 ldfrag(const ushort_t* plane, int row, int kq) {
  const int slot = kq ^ (row & 3);
  return *(const s16x8*)(plane + row * 32 + slot * 8);
}

#define VMCNT4 asm volatile("s_waitcnt vmcnt(4)" ::: "memory")
#define BARRIER asm volatile("s_barrier" ::: "memory")

#define MFMA16(A_, B_, R_)                                                  \
  do {                                                                      \
    __builtin_amdgcn_s_setprio(1);                                          \
    _Pragma("unroll") for (int tm_ = 0; tm_ < 4; ++tm_)                     \
        _Pragma("unroll") for (int tn_ = 0; tn_ < 4; ++tn_)                 \
            acc[(R_) + tm_][tn_] = __builtin_amdgcn_mfma_f32_16x16x32_bf16( \
                A_[tm_], B_[tn_], acc[(R_) + tm_][tn_], 0, 0, 0);           \
    __builtin_amdgcn_s_setprio(0);                                          \
  } while (0)

// issue one plane (2 x global_load_lds, 16B/lane) into next buffer
#define GLA(extra, plo)                                        \
  do {                                                         \
    glds16(srcA0 + (extra) + ko, bn_ + (plo) + wld);           \
    glds16(srcA1 + (extra) + ko, bn_ + (plo) + 8192 + wld);    \
  } while (0)
#define GLW(extra, plo)                                        \
  do {                                                         \
    glds16(srcW0 + (extra) + ko, bn_ + (plo) + wld);           \
    glds16(srcW1 + (extra) + ko, bn_ + (plo) + 8192 + wld);    \
  } while (0)

__global__ __launch_bounds__(512, 2) void lstm_gemm(
    const ushort_t* __restrict__ Whi, const ushort_t* __restrict__ Ahi,
    const float* __restrict__ cold, const float* __restrict__ bx,
    const float* __restrict__ bh, float* __restrict__ out) {
  __shared__ unsigned char smem[131072];

  const int tid = threadIdx.x;
  const int lane = tid & 63;
  const int wid = tid >> 6;
  const int wg = wid & 3;   // gate 0..3
  const int wm = wid >> 2;  // row-half of block
  const int m16 = lane & 15;
  const int kq = lane >> 4;

  // XCD-bijective swizzle: 512 wgs = 8 XCDs x 64
  const int swz = (blockIdx.x & 7) * 64 + (blockIdx.x >> 3);
  const int bm0 = (swz >> 5) * 256;  // batch rows
  const int col0 = (swz & 31) * 64;  // per-gate col block

  // staging lane constants: LDS pos (j*512+tid)*16 <-> (row=j*128+(tid>>2), slot=tid&3)
  const int lrow = tid >> 2;  // 0..127
  const int lslot = tid & 3;
  const int gsl = (lslot ^ (lrow & 3)) << 4;  // pre-swizzled global 16B slot
  const char* Ab = (const char*)Ahi;
  const char* Wb = (const char*)Whi;
  const char* srcA0 = Ab + (size_t)(bm0 + lrow) * 8192 + gsl;
  const char* srcA1 = Ab + (size_t)(bm0 + 128 + lrow) * 8192 + gsl;
  const int wr0 = (lrow >> 6) * 2048 + col0 + (lrow & 63);
  const int wr1 = wr0 + 2 * 2048;  // rows 128..255 -> gates 2,3
  const char* srcW0 = Wb + (size_t)wr0 * 8192 + gsl;
  const char* srcW1 = Wb + (size_t)wr1 * 8192 + gsl;

  const int wld = wid * 1024;  // per-wave LDS staging base within plane

  f32x4 acc[8][4] = {};

  // prologue: stage tile 0 (order Ah, Wh, Al, Wl), wait oldest 4, barrier
  {
    unsigned char* bn_ = smem;
    const int ko = 0;
    GLA(0, 0);
    GLW(0, 32768);
    GLA(ALO_B, 16384);
    GLW(WLO_B, 49152);
  }
  VMCNT4;
  BARRIER;

  for (int t = 0; t < NT; ++t) {
    const int cb = t & 1;
    unsigned char* bc_ = smem + cb * 65536;
    unsigned char* bn_ = smem + (cb ^ 1) * 65536;
    const int ktn = (t + 1 < NT) ? t + 1 : t;  // clamp: dummy re-issue last iter
    const int ko = ktn << 6;                   // k byte offset within a row
    const ushort_t* pAh = (const ushort_t*)(bc_);
    const ushort_t* pAl = (const ushort_t*)(bc_ + 16384);
    const ushort_t* pWh = (const ushort_t*)(bc_ + 32768);
    const ushort_t* pWl = (const ushort_t*)(bc_ + 49152);
    const int ra = wm * 128;
    s16x8 wh[4], wl[4], a0[4], a1[4];

    // phase 1: read wh + ah(mh0); issue Ah(t+1); wait Al(t); mfma hh/mh0
#pragma unroll
    for (int i = 0; i < 4; ++i) wh[i] = ldfrag(pWh, wg * 64 + i * 16 + m16, kq);
#pragma unroll
    for (int i = 0; i < 4; ++i) a0[i] = ldfrag(pAh, ra + i * 16 + m16, kq);
    GLA(0, 0);
    VMCNT4;
    BARRIER;
    MFMA16(a0, wh, 0);
    BARRIER;

    // phase 2: read al(mh0); issue Wh(t+1); wait Wl(t); mfma lh/mh0
#pragma unroll
    for (int i = 0; i < 4; ++i) a1[i] = ldfrag(pAl, ra + i * 16 + m16, kq);
    GLW(0, 32768);
    VMCNT4;
    BARRIER;
    MFMA16(a1, wh, 0);
    BARRIER;

    // phase 3: read wl; issue Al(t+1); mfma hl/mh0
#pragma unroll
    for (int i = 0; i < 4; ++i) wl[i] = ldfrag(pWl, wg * 64 + i * 16 + m16, kq);
    GLA(ALO_B, 16384);
    BARRIER;
    MFMA16(a0, wl, 0);
    BARRIER;

    // phase 4: read ah(mh1); issue Wl(t+1); mfma hh/mh1
#pragma unroll
    for (int i = 0; i < 4; ++i)
      a0[i] = ldfrag(pAh, ra + 64 + i * 16 + m16, kq);
    GLW(WLO_B, 49152);
    BARRIER;
    MFMA16(a0, wh, 4);
    BARRIER;

    // phase 5: read al(mh1); mfma lh/mh1
#pragma unroll
    for (int i = 0; i < 4; ++i)
      a1[i] = ldfrag(pAl, ra + 64 + i * 16 + m16, kq);
    BARRIER;
    MFMA16(a1, wh, 4);
    BARRIER;

    // phase 6: boundary wait (Ah,Wh of t+1 done); mfma hl/mh1
    VMCNT4;
    BARRIER;
    MFMA16(a0, wl, 4);
    BARRIER;
  }

  // ---------------- fused LSTM epilogue ----------------
  __syncthreads();  // drains outstanding dummy loads too
  float* gl = (float*)smem;  // [4][128][64] f32 = 128KB, one row-half at a time
  const int colg = tid & 15;
  const int rr = tid >> 4;  // 0..31
  const int cgl = col0 + colg * 4;
  f32x4 bi = *(const f32x4*)(bx + cgl) + *(const f32x4*)(bh + cgl);
  f32x4 bf_ = *(const f32x4*)(bx + 2048 + cgl) + *(const f32x4*)(bh + 2048 + cgl);
  f32x4 bg = *(const f32x4*)(bx + 4096 + cgl) + *(const f32x4*)(bh + 4096 + cgl);
  f32x4 bo = *(const f32x4*)(bx + 6144 + cgl) + *(const f32x4*)(bh + 6144 + cgl);

#pragma unroll
  for (int hh = 0; hh < 2; ++hh) {
    if (hh) __syncthreads();  // pass-0 reads done before pass-1 writes
    if (wm == hh) {
#pragma unroll
      for (int tm = 0; tm < 8; ++tm)
#pragma unroll
        for (int tn = 0; tn < 4; ++tn) {
          const int r = tm * 16 + kq * 4;
          const int c = tn * 16 + m16;
#pragma unroll
          for (int i = 0; i < 4; ++i)
            gl[wg * 8192 + (r + i) * 64 + c] = acc[tm][tn][i];
        }
    }
    __syncthreads();
#pragma unroll
    for (int j = 0; j < 4; ++j) {
      const int r = rr + j * 32;
      f32x4 gi = *(const f32x4*)&gl[0 * 8192 + r * 64 + colg * 4] + bi;
      f32x4 gf = *(const f32x4*)&gl[1 * 8192 + r * 64 + colg * 4] + bf_;
      f32x4 gg = *(const f32x4*)&gl[2 * 8192 + r * 64 + colg * 4] + bg;
      f32x4 go = *(const f32x4*)&gl[3 * 8192 + r * 64 + colg * 4] + bo;
      const size_t gbase = (size_t)(bm0 + hh * 128 + r) * 2048 + cgl;
      f32x4 cv = *(const f32x4*)(cold + gbase);
      f32x4 cn, hn;
#pragma unroll
      for (int e = 0; e < 4; ++e) {
        float iv = sigmoidf_(gi[e]);
        float fv = sigmoidf_(gf[e]);
        float gv = tanhf(gg[e]);
        float ov = sigmoidf_(go[e]);
        float c2 = fv * cv[e] + iv * gv;
        cn[e] = c2;
        hn[e] = ov * tanhf(c2);
      }
      *(f32x4*)(out + gbase) = hn;
      *(f32x4*)(out + BH_TOT + gbase) = cn;
    }
  }
}

// ---------------- fallback: round-1 kernel (known pass) ----------------
__device__ __forceinline__ void splitw(f32x4 w0, f32x4 w1, s16x8& hi, s16x8& lo) {
  u32x2 h0, l0, h1, l1;
  splitf4(w0, h0, l0);
  splitf4(w1, h1, l1);
  u32x4 hu = {h0[0], h0[1], h1[0], h1[1]};
  u32x4 lu = {l0[0], l0[1], l1[0], l1[1]};
  hi = __builtin_bit_cast(s16x8, hu);
  lo = __builtin_bit_cast(s16x8, lu);
}

__global__ __launch_bounds__(256, 2) void lstm_fused(
    const float* __restrict__ x, const float* __restrict__ h,
    const float* __restrict__ cold, const float* __restrict__ Wx,
    const float* __restrict__ bx, const float* __restrict__ Wh,
    const float* __restrict__ bh, float* __restrict__ out) {
  __shared__ unsigned char smem[69632];
  ushort_t* Ah = (ushort_t*)smem;
  ushort_t* Al = (ushort_t*)(smem + 5120);
  float* gl = (float*)smem;

  const int tid = threadIdx.x;
  const int lane = tid & 63;
  const int wid = tid >> 6;

  const int swz = (blockIdx.x & 7) * 256 + (blockIdx.x >> 3);
  const int bn = swz >> 6;
  const int bm = swz & 63;
  const int row0 = bm * 64;
  const int col0 = bn * 64;

  const int ar0 = tid >> 3;
  const int akc = (tid & 7) << 2;
  const int wcol = lane & 15;
  const int kch = (lane >> 4) << 3;

  f32x4 acc[4][4];
#pragma unroll
  for (int i = 0; i < 4; ++i)
#pragma unroll
    for (int j = 0; j < 4; ++j) acc[i][j] = (f32x4)0.0f;

#pragma unroll
  for (int ph = 0; ph < 2; ++ph) {
    const float* Ap = ph ? h : x;
    const float* Wp = ph ? Wh : Wx;
    const float* arow0 = Ap + (size_t)(row0 + ar0) * 2048 + akc;
    const float* arow1 = arow0 + 32 * 2048;
    const float* wb[4];
#pragma unroll
    for (int tn = 0; tn < 4; ++tn)
      wb[tn] = Wp + (size_t)(wid * 2048 + col0 + tn * 16 + wcol) * 2048 + kch;

    f32x4 a0 = *(const f32x4*)(arow0);
    f32x4 a1 = *(const f32x4*)(arow1);

    for (int kt = 0; kt < 64; ++kt) {
      const int k0 = kt << 5;
      f32x4 wr[4][2];
#pragma unroll
      for (int tn = 0; tn < 4; ++tn) {
        wr[tn][0] = *(const f32x4*)(wb[tn] + k0);
        wr[tn][1] = *(const f32x4*)(wb[tn] + k0 + 4);
      }
      {
        u32x2 hp, lp;
        splitf4(a0, hp, lp);
        *(u32x2*)(Ah + ar0 * 40 + akc) = hp;
        *(u32x2*)(Al + ar0 * 40 + akc) = lp;
        splitf4(a1, hp, lp);
        *(u32x2*)(Ah + (ar0 + 32) * 40 + akc) = hp;
        *(u32x2*)(Al + (ar0 + 32) * 40 + akc) = lp;
      }
      __syncthreads();
      if (kt != 63) {
        a0 = *(const f32x4*)(arow0 + k0 + 32);
        a1 = *(const f32x4*)(arow1 + k0 + 32);
      }
      s16x8 ah[4], al[4];
#pragma unroll
      for (int tm = 0; tm < 4; ++tm) {
        const int off = (tm * 16 + wcol) * 40 + kch;
        ah[tm] = *(const s16x8*)(Ah + off);
        al[tm] = *(const s16x8*)(Al + off);
      }
      s16x8 whh[4], wll[4];
#pragma unroll
      for (int tn = 0; tn < 4; ++tn) splitw(wr[tn][0], wr[tn][1], whh[tn], wll[tn]);
#pragma unroll
      for (int tm = 0; tm < 4; ++tm)
#pragma unroll
        for (int tn = 0; tn < 4; ++tn)
          acc[tm][tn] = __builtin_amdgcn_mfma_f32_16x16x32_bf16(
              ah[tm], whh[tn], acc[tm][tn], 0, 0, 0);
#pragma unroll
      for (int tm = 0; tm < 4; ++tm)
#pragma unroll
        for (int tn = 0; tn < 4; ++tn)
          acc[tm][tn] = __builtin_amdgcn_mfma_f32_16x16x32_bf16(
              ah[tm], wll[tn], acc[tm][tn], 0, 0, 0);
#pragma unroll
      for (int tm = 0; tm < 4; ++tm)
#pragma unroll
        for (int tn = 0; tn < 4; ++tn)
          acc[tm][tn] = __builtin_amdgcn_mfma_f32_16x16x32_bf16(
              al[tm], whh[tn], acc[tm][tn], 0, 0, 0);
      __syncthreads();
    }
  }

  {
    const int rbase = (lane >> 4) << 2;
#pragma unroll
    for (int tm = 0; tm < 4; ++tm)
#pragma unroll
      for (int tn = 0; tn < 4; ++tn) {
        const int r = tm * 16 + rbase;
        const int cc = tn * 16 + wcol;
#pragma unroll
        for (int i = 0; i < 4; ++i)
          gl[wid * 4352 + (r + i) * 68 + cc] = acc[tm][tn][i];
      }
  }
  __syncthreads();

  const int ecol = (tid & 15) << 2;
  const int er0 = tid >> 4;
  const int cg = col0 + ecol;
  f32x4 bi = *(const f32x4*)(bx + cg) + *(const f32x4*)(bh + cg);
  f32x4 bf = *(const f32x4*)(bx + 2048 + cg) + *(const f32x4*)(bh + 2048 + cg);
  f32x4 bg = *(const f32x4*)(bx + 4096 + cg) + *(const f32x4*)(bh + 4096 + cg);
  f32x4 bo = *(const f32x4*)(bx + 6144 + cg) + *(const f32x4*)(bh + 6144 + cg);
#pragma unroll
  for (int j = 0; j < 4; ++j) {
    const int r = er0 + j * 16;
    const size_t gbase = (size_t)(row0 + r) * 2048 + cg;
    f32x4 gi = *(const f32x4*)&gl[0 * 4352 + r * 68 + ecol] + bi;
    f32x4 gf = *(const f32x4*)&gl[1 * 4352 + r * 68 + ecol] + bf;
    f32x4 gg = *(const f32x4*)&gl[2 * 4352 + r * 68 + ecol] + bg;
    f32x4 go = *(const f32x4*)&gl[3 * 4352 + r * 68 + ecol] + bo;
    f32x4 cv = *(const f32x4*)(cold + gbase);
    f32x4 cn, hn;
#pragma unroll
    for (int e = 0; e < 4; ++e) {
      float iv = sigmoidf_(gi[e]);
      float fv = sigmoidf_(gf[e]);
      float gv = tanhf(gg[e]);
      float ov = sigmoidf_(go[e]);
      float c2 = fv * cv[e] + iv * gv;
      cn[e] = c2;
      hn[e] = ov * tanhf(c2);
    }
    *(f32x4*)(out + gbase) = hn;
    *(f32x4*)(out + BH_TOT + gbase) = cn;
  }
}

extern "C" void kernel_launch(void* const* d_in, const int* in_sizes, int n_in,
                              void* d_out, int out_size, void* d_ws,
                              size_t ws_size, hipStream_t stream) {
  const float* x = (const float*)d_in[0];
  const float* h = (const float*)d_in[1];
  const float* c = (const float*)d_in[2];
  const float* Wx = (const float*)d_in[3];
  const float* bx = (const float*)d_in[4];
  const float* Wh = (const float*)d_in[5];
  const float* bh = (const float*)d_in[6];
  float* out = (float*)d_out;

  const size_t NEED = 201326592ULL;  // 192 MB
  if (ws_size >= NEED) {
    ushort_t* base = (ushort_t*)d_ws;
    ushort_t* Whi = base;                // [8192][4096]
    ushort_t* Wlo = base + 33554432;
    ushort_t* Ahi = base + 67108864;     // [4096][4096]
    ushort_t* Alo = base + 83886080;
    hipLaunchKernelGGL(conv_split, dim3(4096), dim3(256), 0, stream, Wx, Whi,
                       Wlo, 8192 * 512, 0);
    hipLaunchKernelGGL(conv_split, dim3(4096), dim3(256), 0, stream, Wh, Whi,
                       Wlo, 8192 * 512, 2048);
    hipLaunchKernelGGL(conv_split, dim3(2048), dim3(256), 0, stream, x, Ahi,
                       Alo, 4096 * 512, 0);
    hipLaunchKernelGGL(conv_split, dim3(2048), dim3(256), 0, stream, h, Ahi,
                       Alo, 4096 * 512, 2048);
    hipLaunchKernelGGL(lstm_gemm, dim3(512), dim3(512), 0, stream, Whi, Ahi, c,
                       bx, bh, out);
  } else {
    hipLaunchKernelGGL(lstm_fused, dim3(2048), dim3(256), 0, stream, x, h, c,
                       Wx, bx, Wh, bh, out);
  }
}

// Round 4
// 893.125 us; speedup vs baseline: 1.3623x; 1.0321x over previous
//
#include <hip/hip_runtime.h>
#include <hip/hip_bf16.h>
#include <stdint.h>

// LSTM cell, MI355X. Two-stage plan:
//   stage 1: convert W=[Wx|Wh] and A=[x|h] to bf16 hi/lo planes in d_ws
//            (fused per-matrix kernels, 16B stores).
//   stage 2: 3-term split-bf16 MFMA GEMM (ah*wh + ah*wl + al*wh), 3-phase
//            schedule (32-MFMA clusters) with counted vmcnt, conflict-free
//            LDS swizzle (key=(row>>1)&3), fused LSTM epilogue.
// Fallback (ws too small): round-1 kernel (known-pass, 1186us).

typedef float        f32x4 __attribute__((ext_vector_type(4)));
typedef short        s16x8 __attribute__((ext_vector_type(8)));
typedef unsigned int u32x4 __attribute__((ext_vector_type(4)));
typedef unsigned int u32x2 __attribute__((ext_vector_type(2)));
typedef unsigned short ushort_t;

#define BH_TOT 8388608   // B*H
#define NT 128           // K-tiles of 32 over K_cat=4096
#define ALO_B 33554432   // Alo - Ahi (bytes)
#define WLO_B 67108864   // Wlo - Whi (bytes)

__device__ __forceinline__ void splitf4(f32x4 v, u32x2& hp, u32x2& lp) {
  unsigned int u0 = __float_as_uint(v[0]), u1 = __float_as_uint(v[1]);
  unsigned int u2 = __float_as_uint(v[2]), u3 = __float_as_uint(v[3]);
  float d0 = v[0] - __uint_as_float(u0 & 0xFFFF0000u);
  float d1 = v[1] - __uint_as_float(u1 & 0xFFFF0000u);
  float d2 = v[2] - __uint_as_float(u2 & 0xFFFF0000u);
  float d3 = v[3] - __uint_as_float(u3 & 0xFFFF0000u);
  hp[0] = (u0 >> 16) | (u1 & 0xFFFF0000u);
  hp[1] = (u2 >> 16) | (u3 & 0xFFFF0000u);
  unsigned int l0 = __float_as_uint(d0), l1 = __float_as_uint(d1);
  unsigned int l2 = __float_as_uint(d2), l3 = __float_as_uint(d3);
  lp[0] = (l0 >> 16) | (l1 & 0xFFFF0000u);
  lp[1] = (l2 >> 16) | (l3 & 0xFFFF0000u);
}

__device__ __forceinline__ float sigmoidf_(float x) {
  return 1.0f / (1.0f + __expf(-x));
}

// ---------------- stage 1: fused split-conversion ----------------
// dhi/dlo rows of 4096: cols 0-2047 from srcA, 2048-4095 from srcB.
// 8 f32 per thread-iter -> one 16B store per plane.
__global__ __launch_bounds__(256) void conv_split2(
    const float* __restrict__ srcA, const float* __restrict__ srcB,
    ushort_t* __restrict__ dhi, ushort_t* __restrict__ dlo, int nGroups) {
  const int stride = gridDim.x * blockDim.x;
  for (int g = blockIdx.x * blockDim.x + threadIdx.x; g < nGroups; g += stride) {
    const int row = g >> 9;
    const int gi = g & 511;
    const int half = gi >> 8;        // 0 => srcA, 1 => srcB
    const int c8 = (gi & 255) << 3;  // col within source
    const float* s = (half ? srcB : srcA) + (size_t)row * 2048 + c8;
    f32x4 v0 = *(const f32x4*)s;
    f32x4 v1 = *(const f32x4*)(s + 4);
    u32x2 h0, l0, h1, l1;
    splitf4(v0, h0, l0);
    splitf4(v1, h1, l1);
    u32x4 hv = {h0[0], h0[1], h1[0], h1[1]};
    u32x4 lv = {l0[0], l0[1], l1[0], l1[1]};
    const size_t off = (size_t)row * 4096 + half * 2048 + c8;
    *(u32x4*)(dhi + off) = hv;
    *(u32x4*)(dlo + off) = lv;
  }
}

// ---------------- stage 2: 3-phase split GEMM ----------------
__device__ __forceinline__ void glds16(const void* g, void* l) {
  __builtin_amdgcn_global_load_lds(
      (const __attribute__((address_space(1))) unsigned int*)g,
      (__attribute__((address_space(3))) unsigned int*)l, 16, 0, 0);
}

// plane [256][32] bf16 (row=64B=4 slots of 16B); key (row>>1)&3 makes
// 16 consecutive rows cover all 8 addr%128 16B slots -> 2-way (free).
__device__ __forceinline__ s16x8 ldfrag(const ushort_t* plane, int row, int kq) {
  const int slot = kq ^ ((row >> 1) & 3);
  return *(const s16x8*)(plane + row * 32 + slot * 8);
}

#define VMCNT2 asm volatile("s_waitcnt vmcnt(2)" ::: "memory")
#define BARRIER asm volatile("s_barrier" ::: "memory")

#define MFMA16(A_, B_, R_)                                                  \
  do {                                                                      \
    _Pragma("unroll") for (int tm_ = 0; tm_ < 4; ++tm_)                     \
        _Pragma("unroll") for (int tn_ = 0; tn_ < 4; ++tn_)                 \
            acc[(R_) + tm_][tn_] = __builtin_amdgcn_mfma_f32_16x16x32_bf16( \
                A_[tm_], B_[tn_], acc[(R_) + tm_][tn_], 0, 0, 0);           \
  } while (0)

// 32-MFMA cluster (two 16-groups) under one setprio bracket
#define CLUSTER(A1_, B1_, R1_, A2_, B2_, R2_) \
  do {                                        \
    __builtin_amdgcn_s_setprio(1);            \
    MFMA16(A1_, B1_, R1_);                    \
    MFMA16(A2_, B2_, R2_);                    \
    __builtin_amdgcn_s_setprio(0);            \
  } while (0)

// issue one plane (2 x global_load_lds, 16B/lane) into next buffer
#define GLA(extra, plo)                                        \
  do {                                                         \
    glds16(srcA0 + (extra) + ko, bn_ + (plo) + wld);           \
    glds16(srcA1 + (extra) + ko, bn_ + (plo) + 8192 + wld);    \
  } while (0)
#define GLW(extra, plo)                                        \
  do {                                                         \
    glds16(srcW0 + (extra) + ko, bn_ + (plo) + wld);           \
    glds16(srcW1 + (extra) + ko, bn_ + (plo) + 8192 + wld);    \
  } while (0)

__global__ __launch_bounds__(512, 2) void lstm_gemm(
    const ushort_t* __restrict__ Whi, const ushort_t* __restrict__ Ahi,
    const float* __restrict__ cold, const float* __restrict__ bx,
    const float* __restrict__ bh, float* __restrict__ out) {
  __shared__ unsigned char smem[131072];

  const int tid = threadIdx.x;
  const int lane = tid & 63;
  const int wid = tid >> 6;
  const int wg = wid & 3;   // gate 0..3
  const int wm = wid >> 2;  // row-half of block
  const int m16 = lane & 15;
  const int kq = lane >> 4;

  // XCD-bijective swizzle: 512 wgs = 8 XCDs x 64
  const int swz = (blockIdx.x & 7) * 64 + (blockIdx.x >> 3);
  const int bm0 = (swz >> 5) * 256;  // batch rows
  const int col0 = (swz & 31) * 64;  // per-gate col block

  // staging: LDS 16B-slot (row=j*128+(tid>>2), slot=tid&3); source is
  // inverse-swizzled so read-side XOR recovers logical k (rule 21).
  const int lrow = tid >> 2;  // 0..127
  const int lslot = tid & 3;
  const int gsl = (lslot ^ ((lrow >> 1) & 3)) << 4;  // pre-swizzled 16B slot
  const char* Ab = (const char*)Ahi;
  const char* Wb = (const char*)Whi;
  const char* srcA0 = Ab + (size_t)(bm0 + lrow) * 8192 + gsl;
  const char* srcA1 = Ab + (size_t)(bm0 + 128 + lrow) * 8192 + gsl;
  const int wr0 = (lrow >> 6) * 2048 + col0 + (lrow & 63);
  const int wr1 = wr0 + 2 * 2048;  // rows 128..255 -> gates 2,3
  const char* srcW0 = Wb + (size_t)wr0 * 8192 + gsl;
  const char* srcW1 = Wb + (size_t)wr1 * 8192 + gsl;

  const int wld = wid * 1024;  // per-wave LDS staging base within plane

  f32x4 acc[8][4] = {};

  // prologue: stage tile 0 (order Ah, Wh, Al, Wl); vmcnt(2) retires
  // Ah,Wh,Al (leaves Wl outstanding); barrier.
  {
    unsigned char* bn_ = smem;
    const int ko = 0;
    GLA(0, 0);
    GLW(0, 32768);
    GLA(ALO_B, 16384);
    GLW(WLO_B, 49152);
  }
  VMCNT2;
  BARRIER;

  for (int t = 0; t < NT; ++t) {
    const int cb = t & 1;
    unsigned char* bc_ = smem + cb * 65536;
    unsigned char* bn_ = smem + (cb ^ 1) * 65536;
    const int ktn = (t + 1 < NT) ? t + 1 : t;  // clamp: dummy re-issue last iter
    const int ko = ktn << 6;                   // k byte offset within a row
    const ushort_t* pAh = (const ushort_t*)(bc_);
    const ushort_t* pAl = (const ushort_t*)(bc_ + 16384);
    const ushort_t* pWh = (const ushort_t*)(bc_ + 32768);
    const ushort_t* pWl = (const ushort_t*)(bc_ + 49152);
    const int ra = wm * 128;
    s16x8 wh[4], wl[4], a0[4], a1[4], a0p[4], a1p[4];

    // ---- phase 1: reads wh, ah(mh0), al(mh0); issue Ah(t+1);
    //      vmcnt(2) retires Wl(t); cluster hh+lh of mh0.
#pragma unroll
    for (int i = 0; i < 4; ++i) wh[i] = ldfrag(pWh, wg * 64 + i * 16 + m16, kq);
#pragma unroll
    for (int i = 0; i < 4; ++i) a0[i] = ldfrag(pAh, ra + i * 16 + m16, kq);
#pragma unroll
    for (int i = 0; i < 4; ++i) a1[i] = ldfrag(pAl, ra + i * 16 + m16, kq);
    GLA(0, 0);
    VMCNT2;
    BARRIER;
    CLUSTER(a0, wh, 0, a1, wh, 0);
    BARRIER;

    // ---- phase 2: reads wl, ah(mh1); issue Wh(t+1), Al(t+1);
    //      cluster hl of mh0 + hh of mh1.
#pragma unroll
    for (int i = 0; i < 4; ++i) wl[i] = ldfrag(pWl, wg * 64 + i * 16 + m16, kq);
#pragma unroll
    for (int i = 0; i < 4; ++i)
      a0p[i] = ldfrag(pAh, ra + 64 + i * 16 + m16, kq);
    GLW(0, 32768);
    GLA(ALO_B, 16384);
    BARRIER;
    CLUSTER(a0, wl, 0, a0p, wh, 4);
    BARRIER;

    // ---- phase 3: reads al(mh1); issue Wl(t+1); vmcnt(2) retires
    //      Ah,Wh,Al(t+1); cluster lh+hl of mh1.
#pragma unroll
    for (int i = 0; i < 4; ++i)
      a1p[i] = ldfrag(pAl, ra + 64 + i * 16 + m16, kq);
    GLW(WLO_B, 49152);
    VMCNT2;
    BARRIER;
    CLUSTER(a1p, wh, 4, a0p, wl, 4);
    BARRIER;
  }

  // ---------------- fused LSTM epilogue ----------------
  __syncthreads();  // drains outstanding dummy loads too
  float* gl = (float*)smem;  // [4][128][64] f32 = 128KB, one row-half at a time
  const int colg = tid & 15;
  const int rr = tid >> 4;  // 0..31
  const int cgl = col0 + colg * 4;
  f32x4 bi = *(const f32x4*)(bx + cgl) + *(const f32x4*)(bh + cgl);
  f32x4 bf_ = *(const f32x4*)(bx + 2048 + cgl) + *(const f32x4*)(bh + 2048 + cgl);
  f32x4 bg = *(const f32x4*)(bx + 4096 + cgl) + *(const f32x4*)(bh + 4096 + cgl);
  f32x4 bo = *(const f32x4*)(bx + 6144 + cgl) + *(const f32x4*)(bh + 6144 + cgl);

#pragma unroll
  for (int hh = 0; hh < 2; ++hh) {
    if (hh) __syncthreads();  // pass-0 reads done before pass-1 writes
    if (wm == hh) {
#pragma unroll
      for (int tm = 0; tm < 8; ++tm)
#pragma unroll
        for (int tn = 0; tn < 4; ++tn) {
          const int r = tm * 16 + kq * 4;
          const int c = tn * 16 + m16;
#pragma unroll
          for (int i = 0; i < 4; ++i)
            gl[wg * 8192 + (r + i) * 64 + c] = acc[tm][tn][i];
        }
    }
    __syncthreads();
#pragma unroll
    for (int j = 0; j < 4; ++j) {
      const int r = rr + j * 32;
      f32x4 gi = *(const f32x4*)&gl[0 * 8192 + r * 64 + colg * 4] + bi;
      f32x4 gf = *(const f32x4*)&gl[1 * 8192 + r * 64 + colg * 4] + bf_;
      f32x4 gg = *(const f32x4*)&gl[2 * 8192 + r * 64 + colg * 4] + bg;
      f32x4 go = *(const f32x4*)&gl[3 * 8192 + r * 64 + colg * 4] + bo;
      const size_t gbase = (size_t)(bm0 + hh * 128 + r) * 2048 + cgl;
      f32x4 cv = *(const f32x4*)(cold + gbase);
      f32x4 cn, hn;
#pragma unroll
      for (int e = 0; e < 4; ++e) {
        float iv = sigmoidf_(gi[e]);
        float fv = sigmoidf_(gf[e]);
        float gv = tanhf(gg[e]);
        float ov = sigmoidf_(go[e]);
        float c2 = fv * cv[e] + iv * gv;
        cn[e] = c2;
        hn[e] = ov * tanhf(c2);
      }
      *(f32x4*)(out + gbase) = hn;
      *(f32x4*)(out + BH_TOT + gbase) = cn;
    }
  }
}

// ---------------- fallback: round-1 kernel (known pass) ----------------
__device__ __forceinline__ void splitw(f32x4 w0, f32x4 w1, s16x8& hi, s16x8& lo) {
  u32x2 h0, l0, h1, l1;
  splitf4(w0, h0, l0);
  splitf4(w1, h1, l1);
  u32x4 hu = {h0[0], h0[1], h1[0], h1[1]};
  u32x4 lu = {l0[0], l0[1], l1[0], l1[1]};
  hi = __builtin_bit_cast(s16x8, hu);
  lo = __builtin_bit_cast(s16x8, lu);
}

__global__ __launch_bounds__(256, 2) void lstm_fused(
    const float* __restrict__ x, const float* __restrict__ h,
    const float* __restrict__ cold, const float* __restrict__ Wx,
    const float* __restrict__ bx, const float* __restrict__ Wh,
    const float* __restrict__ bh, float* __restrict__ out) {
  __shared__ unsigned char smem[69632];
  ushort_t* Ah = (ushort_t*)smem;
  ushort_t* Al = (ushort_t*)(smem + 5120);
  float* gl = (float*)smem;

  const int tid = threadIdx.x;
  const int lane = tid & 63;
  const int wid = tid >> 6;

  const int swz = (blockIdx.x & 7) * 256 + (blockIdx.x >> 3);
  const int bn = swz >> 6;
  const int bm = swz & 63;
  const int row0 = bm * 64;
  const int col0 = bn * 64;

  const int ar0 = tid >> 3;
  const int akc = (tid & 7) << 2;
  const int wcol = lane & 15;
  const int kch = (lane >> 4) << 3;

  f32x4 acc[4][4];
#pragma unroll
  for (int i = 0; i < 4; ++i)
#pragma unroll
    for (int j = 0; j < 4; ++j) acc[i][j] = (f32x4)0.0f;

#pragma unroll
  for (int ph = 0; ph < 2; ++ph) {
    const float* Ap = ph ? h : x;
    const float* Wp = ph ? Wh : Wx;
    const float* arow0 = Ap + (size_t)(row0 + ar0) * 2048 + akc;
    const float* arow1 = arow0 + 32 * 2048;
    const float* wb[4];
#pragma unroll
    for (int tn = 0; tn < 4; ++tn)
      wb[tn] = Wp + (size_t)(wid * 2048 + col0 + tn * 16 + wcol) * 2048 + kch;

    f32x4 a0 = *(const f32x4*)(arow0);
    f32x4 a1 = *(const f32x4*)(arow1);

    for (int kt = 0; kt < 64; ++kt) {
      const int k0 = kt << 5;
      f32x4 wr[4][2];
#pragma unroll
      for (int tn = 0; tn < 4; ++tn) {
        wr[tn][0] = *(const f32x4*)(wb[tn] + k0);
        wr[tn][1] = *(const f32x4*)(wb[tn] + k0 + 4);
      }
      {
        u32x2 hp, lp;
        splitf4(a0, hp, lp);
        *(u32x2*)(Ah + ar0 * 40 + akc) = hp;
        *(u32x2*)(Al + ar0 * 40 + akc) = lp;
        splitf4(a1, hp, lp);
        *(u32x2*)(Ah + (ar0 + 32) * 40 + akc) = hp;
        *(u32x2*)(Al + (ar0 + 32) * 40 + akc) = lp;
      }
      __syncthreads();
      if (kt != 63) {
        a0 = *(const f32x4*)(arow0 + k0 + 32);
        a1 = *(const f32x4*)(arow1 + k0 + 32);
      }
      s16x8 ah[4], al[4];
#pragma unroll
      for (int tm = 0; tm < 4; ++tm) {
        const int off = (tm * 16 + wcol) * 40 + kch;
        ah[tm] = *(const s16x8*)(Ah + off);
        al[tm] = *(const s16x8*)(Al + off);
      }
      s16x8 whh[4], wll[4];
#pragma unroll
      for (int tn = 0; tn < 4; ++tn) splitw(wr[tn][0], wr[tn][1], whh[tn], wll[tn]);
#pragma unroll
      for (int tm = 0; tm < 4; ++tm)
#pragma unroll
        for (int tn = 0; tn < 4; ++tn)
          acc[tm][tn] = __builtin_amdgcn_mfma_f32_16x16x32_bf16(
              ah[tm], whh[tn], acc[tm][tn], 0, 0, 0);
#pragma unroll
      for (int tm = 0; tm < 4; ++tm)
#pragma unroll
        for (int tn = 0; tn < 4; ++tn)
          acc[tm][tn] = __builtin_amdgcn_mfma_f32_16x16x32_bf16(
              ah[tm], wll[tn], acc[tm][tn], 0, 0, 0);
#pragma unroll
      for (int tm = 0; tm < 4; ++tm)
#pragma unroll
        for (int tn = 0; tn < 4; ++tn)
          acc[tm][tn] = __builtin_amdgcn_mfma_f32_16x16x32_bf16(
              al[tm], whh[tn], acc[tm][tn], 0, 0, 0);
      __syncthreads();
    }
  }

  {
    const int rbase = (lane >> 4) << 2;
#pragma unroll
    for (int tm = 0; tm < 4; ++tm)
#pragma unroll
      for (int tn = 0; tn < 4; ++tn) {
        const int r = tm * 16 + rbase;
        const int cc = tn * 16 + wcol;
#pragma unroll
        for (int i = 0; i < 4; ++i)
          gl[wid * 4352 + (r + i) * 68 + cc] = acc[tm][tn][i];
      }
  }
  __syncthreads();

  const int ecol = (tid & 15) << 2;
  const int er0 = tid >> 4;
  const int cg = col0 + ecol;
  f32x4 bi = *(const f32x4*)(bx + cg) + *(const f32x4*)(bh + cg);
  f32x4 bf = *(const f32x4*)(bx + 2048 + cg) + *(const f32x4*)(bh + 2048 + cg);
  f32x4 bg = *(const f32x4*)(bx + 4096 + cg) + *(const f32x4*)(bh + 4096 + cg);
  f32x4 bo = *(const f32x4*)(bx + 6144 + cg) + *(const f32x4*)(bh + 6144 + cg);
#pragma unroll
  for (int j = 0; j < 4; ++j) {
    const int r = er0 + j * 16;
    const size_t gbase = (size_t)(row0 + r) * 2048 + cg;
    f32x4 gi = *(const f32x4*)&gl[0 * 4352 + r * 68 + ecol] + bi;
    f32x4 gf = *(const f32x4*)&gl[1 * 4352 + r * 68 + ecol] + bf;
    f32x4 gg = *(const f32x4*)&gl[2 * 4352 + r * 68 + ecol] + bg;
    f32x4 go = *(const f32x4*)&gl[3 * 4352 + r * 68 + ecol] + bo;
    f32x4 cv = *(const f32x4*)(cold + gbase);
    f32x4 cn, hn;
#pragma unroll
    for (int e = 0; e < 4; ++e) {
      float iv = sigmoidf_(gi[e]);
      float fv = sigmoidf_(gf[e]);
      float gv = tanhf(gg[e]);
      float ov = sigmoidf_(go[e]);
      float c2 = fv * cv[e] + iv * gv;
      cn[e] = c2;
      hn[e] = ov * tanhf(c2);
    }
    *(f32x4*)(out + gbase) = hn;
    *(f32x4*)(out + BH_TOT + gbase) = cn;
  }
}

extern "C" void kernel_launch(void* const* d_in, const int* in_sizes, int n_in,
                              void* d_out, int out_size, void* d_ws,
                              size_t ws_size, hipStream_t stream) {
  const float* x = (const float*)d_in[0];
  const float* h = (const float*)d_in[1];
  const float* c = (const float*)d_in[2];
  const float* Wx = (const float*)d_in[3];
  const float* bx = (const float*)d_in[4];
  const float* Wh = (const float*)d_in[5];
  const float* bh = (const float*)d_in[6];
  float* out = (float*)d_out;

  const size_t NEED = 201326592ULL;  // 192 MB
  if (ws_size >= NEED) {
    ushort_t* base = (ushort_t*)d_ws;
    ushort_t* Whi = base;                // [8192][4096]
    ushort_t* Wlo = base + 33554432;
    ushort_t* Ahi = base + 67108864;     // [4096][4096]
    ushort_t* Alo = base + 83886080;
    hipLaunchKernelGGL(conv_split2, dim3(4096), dim3(256), 0, stream, Wx, Wh,
                       Whi, Wlo, 8192 * 512);
    hipLaunchKernelGGL(conv_split2, dim3(2048), dim3(256), 0, stream, x, h,
                       Ahi, Alo, 4096 * 512);
    hipLaunchKernelGGL(lstm_gemm, dim3(512), dim3(512), 0, stream, Whi, Ahi, c,
                       bx, bh, out);
  } else {
    hipLaunchKernelGGL(lstm_fused, dim3(2048), dim3(256), 0, stream, x, h, c,
                       Wx, bx, Wh, bh, out);
  }
}